// Round 1
// baseline (471.960 us; speedup 1.0000x reference)
//
#include <hip/hip_runtime.h>
#include <stdint.h>

typedef float f32x4 __attribute__((ext_vector_type(4)));
typedef __bf16 bf16x8 __attribute__((ext_vector_type(8)));

// RNE fp32->bf16 pair pack: 2 adds + 1 v_perm per pair.
__device__ __forceinline__ unsigned int pack_bf16_rne(float fa, float fb) {
  unsigned int ua = __float_as_uint(fa);
  ua += 0x7fffu + ((ua >> 16) & 1u);
  unsigned int ub = __float_as_uint(fb);
  ub += 0x7fffu + ((ub >> 16) & 1u);
  return __builtin_amdgcn_perm(ub, ua, 0x07060302u);  // lo16=bf16(fa), hi16=bf16(fb)
}

// W fp32 [256,256] -> bf16 in workspace (128 KB, L2-resident thereafter)
__global__ void wcvt_kernel(const float* __restrict__ W, uint2* __restrict__ Wb) {
  int i = blockIdx.x * blockDim.x + threadIdx.x;  // 4 floats / thread
  float4 v = ((const float4*)W)[i];
  uint2 o;
  o.x = pack_bf16_rne(v.x, v.y);
  o.y = pack_bf16_rne(v.z, v.w);
  Wb[i] = o;
}

// Convert a 32-row x-tile (held in 4 float4/thread) into the swizzled bf16 A
// tile + per-row log_map scale.  Thread t owns float4 #(t + 512*i), i=0..3:
// row = (t>>6) + 8*i (wave-uniform per i), col-f4 = t&63 (== lane).
__device__ __forceinline__ void convert_tile(float4 g0, float4 g1, float4 g2,
                                             float4 g3, int lane, int w,
                                             unsigned char* As, float* a_scale) {
  float p0 = g0.x * g0.x + g0.y * g0.y + g0.z * g0.z + g0.w * g0.w;
  float p1 = g1.x * g1.x + g1.y * g1.y + g1.z * g1.z + g1.w * g1.w;
  float p2 = g2.x * g2.x + g2.y * g2.y + g2.z * g2.z + g2.w * g2.w;
  float p3 = g3.x * g3.x + g3.y * g3.y + g3.z * g3.z + g3.w * g3.w;
  // full-wave butterfly: each p_i is a whole row's ssq afterwards (f32, exact-x)
#pragma unroll
  for (int m = 1; m < 64; m <<= 1) {
    p0 += __shfl_xor(p0, m);
    p1 += __shfl_xor(p1, m);
    p2 += __shfl_xor(p2, m);
    p3 += __shfl_xor(p3, m);
  }
  float pv = p0;
  pv = (lane == 1) ? p1 : pv;
  pv = (lane == 2) ? p2 : pv;
  pv = (lane == 3) ? p3 : pv;
  if (lane < 4) {  // 4 lanes compute 4 rows' atanh scale in parallel
    float xn = fmaxf(sqrtf(pv), 1e-6f);
    float t = fminf(0.1f * xn, 1.0f - 1e-6f);
    a_scale[w + 8 * lane] = atanhf(t) / (0.1f * xn);  // log_map_zero row scale
  }
  // bf16 pack + XOR-swizzled LDS write (row&7 == w for all 4 rows of this wave)
  const int physoff = (((lane >> 1) ^ w) << 4) + (lane & 1) * 8;
#pragma unroll
  for (int i = 0; i < 4; ++i) {
    float4 gg = (i == 0) ? g0 : (i == 1) ? g1 : (i == 2) ? g2 : g3;
    uint2 o;
    o.x = pack_bf16_rne(gg.x, gg.y);
    o.y = pack_bf16_rne(gg.z, gg.w);
    *(uint2*)(As + (w + 8 * i) * 512 + physoff) = o;  // conflict-free (bijective xor)
  }
}

// Persistent streaming kernel: 512 blocks x 512 threads, grid-stride over
// 32-row tiles.  Per wave: output cols w*32..+31; W fragments live in 64 VGPRs
// (loaded once per block from L2) -> no B staging, no B barriers.
// Pipeline per tile (2 barriers): issue next-tile x loads -> MFMA current tile
// -> row-ssq -> B1 -> oscale || convert-next -> B2 -> stores.
__global__ __launch_bounds__(512, 4) void hyper_kernel(
    const float* __restrict__ x, const unsigned short* __restrict__ Wb,
    const float* __restrict__ bias, float* __restrict__ out, int nt) {
  __shared__ __align__(16) unsigned char As[32 * 512];  // 16 KB bf16, swizzled
  __shared__ float a_scale[32];
  __shared__ float rowsq[32][8];
  __shared__ float oscale[32];

  const int tid = threadIdx.x;
  const int w = tid >> 6;     // wave 0..7 -> cols w*32..+31
  const int lane = tid & 63;
  const int l15 = lane & 15;
  const int l4 = lane >> 4;
  const int swz = l15 & 7;

  int tile = blockIdx.x;
  if (tile >= nt) return;

  // ---- W fragments: breg[tc][s] = W row (out col) w*32+tc*16+l15, k=s*32+l4*8
  bf16x8 breg[2][8];
#pragma unroll
  for (int tc = 0; tc < 2; ++tc) {
    const unsigned short* wp = Wb + (w * 32 + tc * 16 + l15) * 256 + l4 * 8;
#pragma unroll
    for (int s = 0; s < 8; ++s) breg[tc][s] = *(const bf16x8*)(wp + s * 32);
  }
  float bv[2];
#pragma unroll
  for (int tc = 0; tc < 2; ++tc) bv[tc] = bias[w * 32 + tc * 16 + l15];

  // ---- prologue: load + convert first tile ----
  {
    const float4* xp = (const float4*)x + (size_t)tile * 2048 + tid;
    float4 g0 = xp[0], g1 = xp[512], g2 = xp[1024], g3 = xp[1536];
    convert_tile(g0, g1, g2, g3, lane, w, As, a_scale);
  }
  __syncthreads();

  for (;;) {
    const int next = tile + (int)gridDim.x;
    const bool hn = next < nt;
    float4 g0, g1, g2, g3;
    if (hn) {  // T14 async-STAGE: issue loads now, consume after the barrier
      const float4* xp = (const float4*)x + (size_t)next * 2048 + tid;
      g0 = xp[0];
      g1 = xp[512];
      g2 = xp[1024];
      g3 = xp[1536];
    }
    __builtin_amdgcn_sched_barrier(0);  // pin the prefetch loads before MFMA

    // ---- GEMM: 16 ds_read_b128 + 32 MFMA per wave ----
    const f32x4 fzero = {0.f, 0.f, 0.f, 0.f};
    f32x4 acc[2][2];
#pragma unroll
    for (int a = 0; a < 2; ++a)
#pragma unroll
      for (int b = 0; b < 2; ++b) acc[a][b] = fzero;

#pragma unroll
    for (int s = 0; s < 8; ++s) {
      bf16x8 af[2];
#pragma unroll
      for (int tr = 0; tr < 2; ++tr) {
        int ar = tr * 16 + l15;
        af[tr] = *(const bf16x8*)(As + ar * 512 + (((s * 4 + l4) ^ swz) << 4));
      }
#pragma unroll
      for (int tr = 0; tr < 2; ++tr)
#pragma unroll
        for (int tc = 0; tc < 2; ++tc)
          acc[tr][tc] = __builtin_amdgcn_mfma_f32_16x16x32_bf16(
              af[tr], breg[tc][s], acc[tr][tc], 0, 0, 0);
    }

    // ---- epilogue p1: a_scale*acc + bias, per-row partial ssq over 32 cols
#pragma unroll
    for (int tr = 0; tr < 2; ++tr)
#pragma unroll
      for (int rg = 0; rg < 4; ++rg) {
        int lr = tr * 16 + l4 * 4 + rg;  // C/D layout: col=l15, row=l4*4+rg
        float as = a_scale[lr];
        float v0 = acc[tr][0][rg] * as + bv[0];
        float v1 = acc[tr][1][rg] * as + bv[1];
        acc[tr][0][rg] = v0;
        acc[tr][1][rg] = v1;
        float s = v0 * v0 + v1 * v1;
        s += __shfl_xor(s, 1);
        s += __shfl_xor(s, 2);
        s += __shfl_xor(s, 4);
        s += __shfl_xor(s, 8);
        if (l15 == 0) rowsq[lr][w] = s;
      }
    __syncthreads();  // B1: rowsq visible; As reads done; drains prefetch vmem

    if (tid < 32) {  // exp_map + project_to_ball row scale
      float ssq = rowsq[tid][0] + rowsq[tid][1] + rowsq[tid][2] + rowsq[tid][3] +
                  rowsq[tid][4] + rowsq[tid][5] + rowsq[tid][6] + rowsq[tid][7];
      float norm = sqrtf(ssq);
      float vn = fmaxf(norm, 1e-6f);
      float a1 = tanhf(0.1f * vn) / (0.1f * vn);
      float rn = fmaxf(norm * a1, 1e-6f);
      float cl = fminf(rn, 10.0f - 2e-6f);
      oscale[tid] = a1 * (cl / rn);
    }
    if (hn) convert_tile(g0, g1, g2, g3, lane, w, As, a_scale);  // next tile
    __syncthreads();  // B2: oscale + next-tile As/a_scale visible

    // ---- stores: 16x 4B, 16 lanes consecutive -> full 64B segments ----
    float* op = out + (size_t)tile * 8192 + w * 32 + l15;
#pragma unroll
    for (int tr = 0; tr < 2; ++tr)
#pragma unroll
      for (int rg = 0; rg < 4; ++rg) {
        int lr = tr * 16 + l4 * 4 + rg;
        float os = oscale[lr];
#pragma unroll
        for (int tc = 0; tc < 2; ++tc)
          op[lr * 256 + tc * 16] = acc[tr][tc][rg] * os;
      }

    if (!hn) break;
    tile = next;
  }
}

extern "C" void kernel_launch(void* const* d_in, const int* in_sizes, int n_in,
                              void* d_out, int out_size, void* d_ws, size_t ws_size,
                              hipStream_t stream) {
  const float* x = (const float*)d_in[0];
  const float* W = (const float*)d_in[1];
  const float* bias = (const float*)d_in[2];
  float* out = (float*)d_out;
  const int N = in_sizes[0] / 256;       // 262144 rows (divisible by 32)
  const int wgrid = in_sizes[1] / 1024;  // 65536 / (256 thr * 4 elem) = 64
  const int nt = N / 32;                 // 8192 tiles of 32 rows

  wcvt_kernel<<<wgrid, 256, 0, stream>>>(W, (uint2*)d_ws);
  const int grid = nt < 512 ? nt : 512;  // 2 blocks/CU, persistent grid-stride
  hyper_kernel<<<grid, 512, 0, stream>>>(x, (const unsigned short*)d_ws, bias,
                                         out, nt);
}